// Round 5
// baseline (426.232 us; speedup 1.0000x reference)
//
#include <hip/hip_runtime.h>
#include <stdint.h>

// Cost volume: out[b,k,h,w] = (1/81) * sum_c x1[b,c,h,w] * x2[b,c,h-i,w-j]
// k = (9i+j) mod 81, i,j in [-4,4], zero-padded x2. B=4 C=128 H=128 W=256 fp32.
//
// R10: 8h x 32w tile, i-split across grid. R5-R9 established time is
// structure-invariant ~87us with all pipes <45%: per-output overhead on a
// too-small tile (10 outputs/thread, 96B/64B requests, 8 barriers/block).
//  - Tile 8h x 32w; 16 waves = (hl 0..7) x (m-half 0..1). Each wave: one
//    16-col m-tile, ALL i of its block's i-half, 2 n-tiles -> acc 40 f32
//    (5i x 2nt x 4) stays under the 128-VGPR cliff (R2/R3 spill mode).
//  - i-range split across GRID: blockIdx.x bit3 = ihalf (i in {-4..0} /
//    {1..4}). Costs x1 re-fetch + 8 dup x2 rows (paired blocks dispatch-
//    adjacent -> L2 absorbs); buys the small accumulator.
//  - Contiguity: x2 staging rows 160B (was 96), x1 128B (was 64), out
//    stores 128B (was 64).
//  - Keeps: counted BAR (no vmcnt drain), cvt_pk_bf16, setprio, and
//    conflict-tuned strides: KSTR=38 ush (odd word-stride -> frag reads
//    16 distinct banks), A_ROW=1220, B_ROW=1826, scratch m-stride 50 /
//    hl-stride 1601 (scatter banks 8q+ja <=2-way; readback 2-way).
//
// Toeplitz: D[m][n] = sum_c x1[c, w0+m] * x2[c, h-i, w0-4+n], out(w0+m, j)
//   = D[m][m+4-j]. Staged B cols 0..39 (w0-4..w0+35); n-tile 2 cols 40..47
//   read garbage, their ja is always <0 -> never stored (junk acc slots).

#define HH 128
#define WW 256
#define HW 32768
#define DD 81
#define NT 1024

typedef __attribute__((ext_vector_type(8))) short short8;
typedef __attribute__((ext_vector_type(4))) float float4v;

// staging geometry (ushorts)
#define KSTR 38         // 32 bf16 ch + 6 pad; word-stride 19 (odd)
#define A_ROW 1220      // 32 m * 38 + 4 pad   (word-stride 610 = 2 mod 32)
#define B_ROW 1826      // 48 col * 38 + 2 pad (word-stride 913 = 17 mod 32)
#define B_BASE 9760     // A region = 8 * 1220
#define SMEM_USH 31672  // 9760 + 12 * 1826 = 63344 B
// epilogue scratch: [8 hl][32 m][45 kl], m-stride 50, hl-stride 1601 floats
#define EP_M 50
#define EP_H 1601

// LDS-only barrier: does NOT drain vmcnt (prefetch stays in flight).
#define BAR()                                                \
  {                                                          \
    asm volatile("s_waitcnt lgkmcnt(0)" ::: "memory");       \
    __builtin_amdgcn_s_barrier();                            \
    asm volatile("" ::: "memory");                           \
  }

__device__ __forceinline__ uint32_t cvt_pk_bf16(float lo, float hi) {
  uint32_t r;
  asm("v_cvt_pk_bf16_f32 %0, %1, %2" : "=v"(r) : "v"(lo), "v"(hi));
  return r;
}

__global__ __launch_bounds__(NT, 4) void cost_volume_kernel(
    const float* __restrict__ x1, const float* __restrict__ x2,
    float* __restrict__ out, const float* __restrict__ zws) {
  __shared__ unsigned short smem[SMEM_USH];

  const int b = blockIdx.z;
  const int ihalf = blockIdx.x >> 3;       // 0: i=-4..0, 1: i=1..4
  const int w0 = (blockIdx.x & 7) * 32;
  const int h0 = blockIdx.y * 8;
  const int t = threadIdx.x;
  const int wid = t >> 6;
  const int hl = wid & 7;
  const int mtw = wid >> 3;                // m-half: m in [16*mtw, 16*mtw+15]
  const int lane = t & 63;
  const int n16 = lane & 15;
  const int quad = lane >> 4;
  const int NI = ihalf ? 4 : 5;
  const int roff = ihalf ? 3 : 4;          // staged B row = hl + roff - ii
  const int ihoff = ihalf ? -4 : 0;        // staged h2 = h0 + ihoff + row

  const float* x1b = x1 + (size_t)b * 128 * HW;
  const float* x2b = x2 + (size_t)b * 128 * HW;

  // ---- staging task decode (chunk-invariant). 2944 tasks: 1024 A + 1920 B.
  // s0: A task t; s1: B task t; s2: B task 1024+t (only t<896 -> waves 0-13)
  const bool has3 = (t < 896);
  const float* tbase[3];
  int tgoff[3], tlds[3], tcp[3];
  bool tok[3];
  {  // s0: x1, rows 8 x f4 8 x cp 16 (per-wave: 8 rows x 128B contiguous)
    const int cp = t >> 6, rem = t & 63, row = rem >> 3, f4 = rem & 7;
    tbase[0] = x1b;
    tgoff[0] = (h0 + row) * WW + w0 + 4 * f4;
    tlds[0] = row * A_ROW + f4 * (4 * KSTR) + 2 * cp;
    tcp[0] = cp;
    tok[0] = true;
  }
#pragma unroll
  for (int s = 1; s < 3; ++s) {  // x2: rows 12 x f4 10 x cp 16 (160B rows)
    const int tb = (s - 1) * 1024 + t;
    const int cp = tb / 120, rem = tb - 120 * cp, row = rem / 10,
              f4 = rem - 10 * row;
    const int h2 = h0 + ihoff + row;
    const int wg = w0 - 4 + 4 * f4;
    tbase[s] = x2b;
    tgoff[s] = h2 * WW + wg;
    tlds[s] = B_BASE + row * B_ROW + f4 * (4 * KSTR) + 2 * cp;
    tcp[s] = cp;
    tok[s] = (tb < 1920) && ((unsigned)h2 < (unsigned)HH) &&
             ((unsigned)wg <= (unsigned)(WW - 4));
  }

  float4v acc[5][2];
#pragma unroll
  for (int ii = 0; ii < 5; ++ii) {
    acc[ii][0] = (float4v){0.f, 0.f, 0.f, 0.f};
    acc[ii][1] = (float4v){0.f, 0.f, 0.f, 0.f};
  }

  float4 va[3], vb[3];

#define LOADSET(C0)                                                            \
  {                                                                            \
    _Pragma("unroll") for (int s = 0; s < 3; ++s) {                            \
      if (s < 2 || has3) {                                                     \
        const float* p =                                                       \
            tok[s] ? tbase[s] + (size_t)((C0) + 2 * tcp[s]) * HW + tgoff[s]    \
                   : zws;                                                      \
        const float* q = tok[s] ? p + HW : zws;                                \
        va[s] = *(const float4*)p;                                             \
        vb[s] = *(const float4*)q;                                             \
      }                                                                        \
    }                                                                          \
  }

#define CONVSET()                                                              \
  {                                                                            \
    _Pragma("unroll") for (int s = 0; s < 3; ++s) {                            \
      if (s < 2 || has3) {                                                     \
        unsigned short* dst = smem + tlds[s];                                  \
        const float4 fa = va[s];                                               \
        const float4 fb = vb[s];                                               \
        *(uint32_t*)(dst + 0 * KSTR) = cvt_pk_bf16(fa.x, fb.x);                \
        *(uint32_t*)(dst + 1 * KSTR) = cvt_pk_bf16(fa.y, fb.y);                \
        *(uint32_t*)(dst + 2 * KSTR) = cvt_pk_bf16(fa.z, fb.z);                \
        *(uint32_t*)(dst + 3 * KSTR) = cvt_pk_bf16(fa.w, fb.w);                \
      }                                                                        \
    }                                                                          \
  }

#define COMPUTE()                                                              \
  {                                                                            \
    const short8 a =                                                           \
        *(const short8*)(smem + hl * A_ROW + (16 * mtw + n16) * KSTR +         \
                         quad * 8);                                            \
    __builtin_amdgcn_s_setprio(1);                                            \
    _Pragma("unroll 5") for (int ii = 0; ii < 5; ++ii) {                       \
      if (ii >= NI) break;                                                     \
      const int r = hl + roff - ii;                                            \
      const unsigned short* bp =                                               \
          smem + B_BASE + r * B_ROW + n16 * KSTR + quad * 8;                   \
      const short8 b0 = *(const short8*)(bp + (16 * mtw) * KSTR);              \
      const short8 b1 = *(const short8*)(bp + (16 * mtw + 16) * KSTR);         \
      acc[ii][0] =                                                             \
          __builtin_amdgcn_mfma_f32_16x16x32_bf16(a, b0, acc[ii][0], 0, 0, 0); \
      acc[ii][1] =                                                             \
          __builtin_amdgcn_mfma_f32_16x16x32_bf16(a, b1, acc[ii][1], 0, 0, 0); \
    }                                                                          \
    __builtin_amdgcn_s_setprio(0);                                            \
  }

  // ---- main loop: 4 chunks of 32 channels, single buffer, counted bars ----
  LOADSET(0);

  CONVSET();      // waits only its own loads
  LOADSET(32);    // chunk 1 in flight across compute
  BAR();
  COMPUTE();
  BAR();

  CONVSET();
  LOADSET(64);
  BAR();
  COMPUTE();
  BAR();

  CONVSET();
  LOADSET(96);
  BAR();
  COMPUTE();
  BAR();

  CONVSET();
  BAR();
  COMPUTE();
  BAR();  // all frag reads done; reuse smem as fp32 scratch

  // ---- epilogue: scatter D to LDS scratch [hl][m 32][kl 45], coalesced out -
  float* scratch = (float*)smem;  // max idx 12801 f = 51204 B < 63344 B
  const float sc = 1.0f / 81.0f;
#pragma unroll 5
  for (int ii = 0; ii < 5; ++ii) {
    if (ii >= NI) break;
    const float av0[4] = {acc[ii][0].x, acc[ii][0].y, acc[ii][0].z,
                          acc[ii][0].w};
    const float av1[4] = {acc[ii][1].x, acc[ii][1].y, acc[ii][1].z,
                          acc[ii][1].w};
#pragma unroll
    for (int reg = 0; reg < 4; ++reg) {
      const int mr = quad * 4 + reg;
      const int m = 16 * mtw + mr;
      // n-tile 0 (n = 16*mtw + n16): ja = mr + 4 - n16 + 4
      {
        const unsigned ja = (unsigned)(mr + 8 - n16);
        if (ja < 9u)
          scratch[hl * EP_H + m * EP_M + ii * 9 + (int)ja] = av0[reg] * sc;
      }
      // n-tile 1 (n = 16*mtw + 16 + n16): ja = mr - 12 - n16 + 4
      {
        const unsigned ja = (unsigned)(mr - 8 - n16);
        if (ja < 9u)
          scratch[hl * EP_H + m * EP_M + ii * 9 + (int)ja] = av1[reg] * sc;
      }
    }
  }
  BAR();

  // write-out: f -> (kl, hlx, mg); 4 scalar LDS reads -> 128B global stores
  const int KL = NI * 9;  // 45 or 36
  const int F4T = 64 * KL;
  for (int f = t; f < F4T; f += NT) {
    const int mg = f & 7;
    const int hlx = (f >> 3) & 7;
    const int kl = f >> 6;
    float4 v;
    v.x = scratch[hlx * EP_H + (4 * mg + 0) * EP_M + kl];
    v.y = scratch[hlx * EP_H + (4 * mg + 1) * EP_M + kl];
    v.z = scratch[hlx * EP_H + (4 * mg + 2) * EP_M + kl];
    v.w = scratch[hlx * EP_H + (4 * mg + 3) * EP_M + kl];
    const int kk = (kl + 45 * ihalf + 41) % 81;
    *(float4*)(out + (((size_t)b * DD + kk) * HH + (h0 + hlx)) * WW + w0 +
               4 * mg) = v;
  }
}

extern "C" void kernel_launch(void* const* d_in, const int* in_sizes, int n_in,
                              void* d_out, int out_size, void* d_ws,
                              size_t ws_size, hipStream_t stream) {
  const float* x1 = (const float*)d_in[0];
  const float* x2 = (const float*)d_in[1];
  float* out = (float*)d_out;

  // zero 256 B of workspace: OOB staging lanes read zeros from here
  hipMemsetAsync(d_ws, 0, 256, stream);

  // grid.x: 8 w-tiles x 2 i-halves; 16 h-tiles; 4 batches = 1024 blocks
  dim3 grid(16, 16, 4);
  dim3 block(NT);
  hipLaunchKernelGGL(cost_volume_kernel, grid, block, 0, stream, x1, x2, out,
                     (const float*)d_ws);
}

// Round 6
// 255.455 us; speedup vs baseline: 1.6685x; 1.6685x over previous
//
#include <hip/hip_runtime.h>
#include <stdint.h>

// Cost volume: out[b,k,h,w] = (1/81) * sum_c x1[b,c,h,w] * x2[b,c,h-i,w-j]
// k = (9i+j) mod 81, i,j in [-4,4], zero-padded x2. B=4 C=128 H=128 W=256 fp32.
//
// R11 = R10 with the accumulator spill removed. R10's VGPR_Count=36 +
// WRITE_SIZE 794MB + hbm_bytes 1.24GB was rule-#20 scratch spill: the
// "#pragma unroll 5 + if (ii >= NI) break" pattern with RUNTIME NI (from
// blockIdx.x) kept ii dynamic -> acc[ii] in local memory -> every chunk
// round-tripped the 40-float accumulator through HBM.
//  - Fix: ihalf is now a TEMPLATE parameter; two 512-block launches
//    (cost_volume_kernel<0>: i=-4..0, <1>: i=1..4), back-to-back on the
//    stream. Each launch = exactly one resident wave of blocks (2/CU LDS).
//    All ii-loops statically bounded; acc[NI][2] fully in registers.
//  - Structure unchanged from R10: tile 8h x 32w, 16 waves = hl x m-half,
//    acc 40 f32 max; x2 staging rows 160B, x1 128B, out stores 128B;
//    counted BAR (no vmcnt drain), cvt_pk_bf16, setprio, conflict-tuned
//    strides (KSTR=38 odd-word, scratch m-stride 50 / hl-stride 1601).
//
// Toeplitz: D[m][n] = sum_c x1[c, w0+m] * x2[c, h-i, w0-4+n], out(w0+m, j)
//   = D[m][m+4-j]. Staged B cols 0..39 (w0-4..w0+35); n-tile-1 cols >39
//   read garbage but their ja check always fails -> junk acc slots only.

#define HH 128
#define WW 256
#define HW 32768
#define DD 81
#define NT 1024

typedef __attribute__((ext_vector_type(8))) short short8;
typedef __attribute__((ext_vector_type(4))) float float4v;

// staging geometry (ushorts)
#define KSTR 38         // 32 bf16 ch + 6 pad; word-stride 19 (odd)
#define A_ROW 1220      // 32 m * 38 + 4 pad   (word-stride 610 = 2 mod 32)
#define B_ROW 1826      // 48 col * 38 + 2 pad (word-stride 913 = 17 mod 32)
#define B_BASE 9760     // A region = 8 * 1220
#define SMEM_USH 31672  // 9760 + 12 * 1826 = 63344 B
// epilogue scratch: [8 hl][32 m][45 kl], m-stride 50, hl-stride 1601 floats
#define EP_M 50
#define EP_H 1601

// LDS-only barrier: does NOT drain vmcnt (prefetch stays in flight).
#define BAR()                                                \
  {                                                          \
    asm volatile("s_waitcnt lgkmcnt(0)" ::: "memory");       \
    __builtin_amdgcn_s_barrier();                            \
    asm volatile("" ::: "memory");                           \
  }

__device__ __forceinline__ uint32_t cvt_pk_bf16(float lo, float hi) {
  uint32_t r;
  asm("v_cvt_pk_bf16_f32 %0, %1, %2" : "=v"(r) : "v"(lo), "v"(hi));
  return r;
}

template <int IHALF>
__global__ __launch_bounds__(NT, 4) void cost_volume_kernel(
    const float* __restrict__ x1, const float* __restrict__ x2,
    float* __restrict__ out, const float* __restrict__ zws) {
  __shared__ unsigned short smem[SMEM_USH];

  constexpr int NI = IHALF ? 4 : 5;     // i = ii + (IHALF ? 1 : -4)
  constexpr int ROFF = IHALF ? 3 : 4;   // staged B row = hl + ROFF - ii
  constexpr int IHOFF = IHALF ? -4 : 0; // staged h2 = h0 + IHOFF + row
  constexpr int KL = NI * 9;

  const int b = blockIdx.z;
  const int w0 = blockIdx.x * 32;
  const int h0 = blockIdx.y * 8;
  const int t = threadIdx.x;
  const int wid = t >> 6;
  const int hl = wid & 7;
  const int mtw = wid >> 3;  // m-half: m in [16*mtw, 16*mtw+15]
  const int lane = t & 63;
  const int n16 = lane & 15;
  const int quad = lane >> 4;

  const float* x1b = x1 + (size_t)b * 128 * HW;
  const float* x2b = x2 + (size_t)b * 128 * HW;

  // ---- staging task decode (chunk-invariant). 2944 tasks: 1024 A + 1920 B.
  // s0: A task t; s1: B task t; s2: B task 1024+t (only t<896 -> waves 0-13)
  const bool has3 = (t < 896);
  const float* tbase[3];
  int tgoff[3], tlds[3], tcp[3];
  bool tok[3];
  {  // s0: x1, cp 16 x row 8 x f4 8 (per-wave: 8 rows x 128B contiguous)
    const int cp = t >> 6, rem = t & 63, row = rem >> 3, f4 = rem & 7;
    tbase[0] = x1b;
    tgoff[0] = (h0 + row) * WW + w0 + 4 * f4;
    tlds[0] = row * A_ROW + f4 * (4 * KSTR) + 2 * cp;
    tcp[0] = cp;
    tok[0] = true;
  }
#pragma unroll
  for (int s = 1; s < 3; ++s) {  // x2: cp 16 x row 12 x f4 10 (160B rows)
    const int tb = (s - 1) * 1024 + t;
    const int cp = tb / 120, rem = tb - 120 * cp, row = rem / 10,
              f4 = rem - 10 * row;
    const int h2 = h0 + IHOFF + row;
    const int wg = w0 - 4 + 4 * f4;
    tbase[s] = x2b;
    tgoff[s] = h2 * WW + wg;
    tlds[s] = B_BASE + row * B_ROW + f4 * (4 * KSTR) + 2 * cp;
    tcp[s] = cp;
    tok[s] = (tb < 1920) && ((unsigned)h2 < (unsigned)HH) &&
             ((unsigned)wg <= (unsigned)(WW - 4));
  }

  float4v acc[NI][2];
#pragma unroll
  for (int ii = 0; ii < NI; ++ii) {
    acc[ii][0] = (float4v){0.f, 0.f, 0.f, 0.f};
    acc[ii][1] = (float4v){0.f, 0.f, 0.f, 0.f};
  }

  float4 va[3], vb[3];

#define LOADSET(C0)                                                            \
  {                                                                            \
    _Pragma("unroll") for (int s = 0; s < 3; ++s) {                            \
      if (s < 2 || has3) {                                                     \
        const float* p =                                                       \
            tok[s] ? tbase[s] + (size_t)((C0) + 2 * tcp[s]) * HW + tgoff[s]    \
                   : zws;                                                      \
        const float* q = tok[s] ? p + HW : zws;                                \
        va[s] = *(const float4*)p;                                             \
        vb[s] = *(const float4*)q;                                             \
      }                                                                        \
    }                                                                          \
  }

#define CONVSET()                                                              \
  {                                                                            \
    _Pragma("unroll") for (int s = 0; s < 3; ++s) {                            \
      if (s < 2 || has3) {                                                     \
        unsigned short* dst = smem + tlds[s];                                  \
        const float4 fa = va[s];                                               \
        const float4 fb = vb[s];                                               \
        *(uint32_t*)(dst + 0 * KSTR) = cvt_pk_bf16(fa.x, fb.x);                \
        *(uint32_t*)(dst + 1 * KSTR) = cvt_pk_bf16(fa.y, fb.y);                \
        *(uint32_t*)(dst + 2 * KSTR) = cvt_pk_bf16(fa.z, fb.z);                \
        *(uint32_t*)(dst + 3 * KSTR) = cvt_pk_bf16(fa.w, fb.w);                \
      }                                                                        \
    }                                                                          \
  }

#define COMPUTE()                                                              \
  {                                                                            \
    const short8 a =                                                           \
        *(const short8*)(smem + hl * A_ROW + (16 * mtw + n16) * KSTR +         \
                         quad * 8);                                            \
    __builtin_amdgcn_s_setprio(1);                                             \
    _Pragma("unroll") for (int ii = 0; ii < NI; ++ii) {                        \
      const int r = hl + ROFF - ii;                                            \
      const unsigned short* bp =                                               \
          smem + B_BASE + r * B_ROW + n16 * KSTR + quad * 8;                   \
      const short8 b0 = *(const short8*)(bp + (16 * mtw) * KSTR);              \
      const short8 b1 = *(const short8*)(bp + (16 * mtw + 16) * KSTR);         \
      acc[ii][0] =                                                             \
          __builtin_amdgcn_mfma_f32_16x16x32_bf16(a, b0, acc[ii][0], 0, 0, 0); \
      acc[ii][1] =                                                             \
          __builtin_amdgcn_mfma_f32_16x16x32_bf16(a, b1, acc[ii][1], 0, 0, 0); \
    }                                                                          \
    __builtin_amdgcn_s_setprio(0);                                             \
  }

  // ---- main loop: 4 chunks of 32 channels, single buffer, counted bars ----
  LOADSET(0);

  CONVSET();      // waits only its own loads (vmcnt counted by compiler)
  LOADSET(32);    // chunk 1 in flight across compute
  BAR();
  COMPUTE();
  BAR();

  CONVSET();
  LOADSET(64);
  BAR();
  COMPUTE();
  BAR();

  CONVSET();
  LOADSET(96);
  BAR();
  COMPUTE();
  BAR();

  CONVSET();
  BAR();
  COMPUTE();
  BAR();  // all frag reads done; reuse smem as fp32 scratch

  // ---- epilogue: scatter D to LDS scratch [hl][m 32][kl], coalesced out ----
  float* scratch = (float*)smem;  // max idx 12801 f = 51204 B < 63344 B
  const float sc = 1.0f / 81.0f;
#pragma unroll
  for (int ii = 0; ii < NI; ++ii) {
    const float av0[4] = {acc[ii][0].x, acc[ii][0].y, acc[ii][0].z,
                          acc[ii][0].w};
    const float av1[4] = {acc[ii][1].x, acc[ii][1].y, acc[ii][1].z,
                          acc[ii][1].w};
#pragma unroll
    for (int reg = 0; reg < 4; ++reg) {
      const int mr = quad * 4 + reg;
      const int m = 16 * mtw + mr;
      // n-tile 0 (n = 16*mtw + n16): ja = mr + 4 - n16 + 4
      {
        const unsigned ja = (unsigned)(mr + 8 - n16);
        if (ja < 9u)
          scratch[hl * EP_H + m * EP_M + ii * 9 + (int)ja] = av0[reg] * sc;
      }
      // n-tile 1 (n = 16*mtw + 16 + n16): ja = mr - 12 - n16 + 4
      {
        const unsigned ja = (unsigned)(mr - 8 - n16);
        if (ja < 9u)
          scratch[hl * EP_H + m * EP_M + ii * 9 + (int)ja] = av1[reg] * sc;
      }
    }
  }
  BAR();

  // write-out: f -> (kl, hlx, mg); 4 scalar LDS reads -> 128B global stores
  constexpr int F4T = 64 * KL;
  for (int f = t; f < F4T; f += NT) {
    const int mg = f & 7;
    const int hlx = (f >> 3) & 7;
    const int kl = f >> 6;
    float4 v;
    v.x = scratch[hlx * EP_H + (4 * mg + 0) * EP_M + kl];
    v.y = scratch[hlx * EP_H + (4 * mg + 1) * EP_M + kl];
    v.z = scratch[hlx * EP_H + (4 * mg + 2) * EP_M + kl];
    v.w = scratch[hlx * EP_H + (4 * mg + 3) * EP_M + kl];
    const int kk = (kl + 45 * IHALF + 41) % 81;
    *(float4*)(out + (((size_t)b * DD + kk) * HH + (h0 + hlx)) * WW + w0 +
               4 * mg) = v;
  }
}

extern "C" void kernel_launch(void* const* d_in, const int* in_sizes, int n_in,
                              void* d_out, int out_size, void* d_ws,
                              size_t ws_size, hipStream_t stream) {
  const float* x1 = (const float*)d_in[0];
  const float* x2 = (const float*)d_in[1];
  float* out = (float*)d_out;

  // zero 256 B of workspace: OOB staging lanes read zeros from here
  hipMemsetAsync(d_ws, 0, 256, stream);

  // two launches: ihalf template split (keeps NI compile-time -> no spill)
  // each: 8 w-tiles x 16 h-tiles x 4 batches = 512 blocks = one full
  // resident wave at 2 blocks/CU.
  dim3 grid(8, 16, 4);
  dim3 block(NT);
  hipLaunchKernelGGL((cost_volume_kernel<0>), grid, block, 0, stream, x1, x2,
                     out, (const float*)d_ws);
  hipLaunchKernelGGL((cost_volume_kernel<1>), grid, block, 0, stream, x1, x2,
                     out, (const float*)d_ws);
}

// Round 7
// 201.685 us; speedup vs baseline: 2.1134x; 1.2666x over previous
//
#include <hip/hip_runtime.h>
#include <stdint.h>

// Cost volume: out[b,k,h,w] = (1/81) * sum_c x1[b,c,h,w] * x2[b,c,h-i,w-j]
// k = (9i+j) mod 81, i,j in [-4,4], zero-padded x2. B=4 C=128 H=128 W=256 fp32.
//
// R12: block-concurrency fix. R5-R11 series shows time = blocks/CU x ~22us
// per-block SERIAL latency (R11: halving blocks/launch left launch time
// unchanged), occupancy ~40% in every config -> effectively ONE 16-wave
// block per CU at a time; all intra-block structure was invariant because
// per-block exposed latency is the unit of time.
//  - Block 768 thr = 12 waves = (hl 0..3) x (i-third g 0..2); tile 4h x 16w.
//    acc 3i x 2nt x 4 = 24 f32; LDS 36.4 KB; __launch_bounds__(768,6)
//    -> 2 blocks/CU co-resident (24/32 waves), 8 blocks/CU total = 4 rounds
//    of 2-deep overlap with staggered phases replacing serial execution.
//  - Cost accepted: 4h-tile x2 halo (12 staged rows per 4 output rows,
//    was 16 per 8) -> FETCH +~40%; BW has 2.3x headroom. h-neighbors land
//    on the same XCD by default dispatch (flat id +16 = 0 mod 8).
//  - Everything proven kept verbatim: Toeplitz window/frag math, c-pair
//    packed bf16 staging, counted BAR (no vmcnt drain), cvt_pk_bf16,
//    setprio, KSTR=40 strides, epilogue scratch [hl][m][kk] (EP_M 82 /
//    EP_H 1313).
//
// Toeplitz: D[m][n] = sum_c x1[c, w0+m] * x2[c, h-i, w0-4+n], out(w0+m, j)
//   = D[m][m+4-j]; window 24 cols = 2x mfma_f32_16x16x32_bf16 (tile1 cols
//   24..31 junk, ja-guard never stores them).
// i-thirds: g=0: i{-4,-3,-2}, g=1: i{-1,0,1}, g=2: i{2,3,4}; i = 3g-4+ii.
// Staged B row r = hl + (8-3g) - ii, r in [0,12); h2 = h0 - 4 + r.

#define HH 128
#define WW 256
#define HW 32768
#define DD 81
#define NT 768

typedef __attribute__((ext_vector_type(8))) short short8;
typedef __attribute__((ext_vector_type(4))) float float4v;

// staging geometry (ushorts)
#define KSTR 40          // 32 bf16 ch + 8 pad
#define A_ROW 648        // 16 m * 40 + 8 pad
#define B_BASE 2592      // A region = 4 * 648
#define B_ROW 1288       // 32 col * 40 + 8 pad (cols 24..31 junk-alloc)
#define DUMP_USH 18048   // invalid slot-1 staging writes land in this pad
#define SMEM_USH 18176   // 2592 + 12*1288 + 128 pad = 36352 B
// epilogue scratch: [4 hl][16 m][81 kk], m-stride 82, hl-stride 1313 floats
#define EP_M 82
#define EP_H 1313        // scratch 4*1313 = 5252 f = 21008 B < 36352 B

// LDS-only barrier: does NOT drain vmcnt (prefetch stays in flight).
#define BAR()                                                \
  {                                                          \
    asm volatile("s_waitcnt lgkmcnt(0)" ::: "memory");       \
    __builtin_amdgcn_s_barrier();                            \
    asm volatile("" ::: "memory");                           \
  }

__device__ __forceinline__ uint32_t cvt_pk_bf16(float lo, float hi) {
  uint32_t r;
  asm("v_cvt_pk_bf16_f32 %0, %1, %2" : "=v"(r) : "v"(lo), "v"(hi));
  return r;
}

__global__ __launch_bounds__(NT, 6) void cost_volume_kernel(
    const float* __restrict__ x1, const float* __restrict__ x2,
    float* __restrict__ out, const float* __restrict__ zws) {
  __shared__ unsigned short smem[SMEM_USH];

  const int b = blockIdx.z;
  const int h0 = blockIdx.y * 4;
  const int w0 = blockIdx.x * 16;
  const int t = threadIdx.x;
  const int wid = t >> 6;
  const int hl = wid & 3;
  const int g = wid >> 2;        // i-third: i = 3g - 4 + ii
  const int roff = 8 - 3 * g;    // staged B row = hl + roff - ii
  const int lane = t & 63;
  const int n16 = lane & 15;
  const int quad = lane >> 4;

  const float* x1b = x1 + (size_t)b * 128 * HW;
  const float* x2b = x2 + (size_t)b * 128 * HW;

  // ---- staging task decode (chunk-invariant). 1408 c-pair tasks/chunk:
  //   A (x1): 256 = cp16 x row4 x f4 4 ; B (x2): 1152 = cp16 x row12 x f4 6
  // slot0: task t; slot1: task t+768 (valid t<640, always a B task).
  const float* tbase[2];
  int tgoff[2], tlds[2], tcp[2];
  bool tok[2];
#pragma unroll
  for (int s = 0; s < 2; ++s) {
    const int tau = t + s * NT;
    if (tau < 256) {
      const int cp = tau >> 4, rem = tau & 15, row = rem >> 2, f4 = rem & 3;
      tbase[s] = x1b;
      tgoff[s] = (h0 + row) * WW + w0 + 4 * f4;
      tlds[s] = row * A_ROW + f4 * (4 * KSTR) + 2 * cp;
      tcp[s] = cp;
      tok[s] = true;
    } else {
      const int tb = tau - 256;  // 0..1151 valid
      const int cp = tb / 72, rem = tb - 72 * cp, row = rem / 6,
                f4 = rem - 6 * row;
      const int h2 = h0 - 4 + row;
      const int wg = w0 - 4 + 4 * f4;
      const bool valid = (tb < 1152) && ((unsigned)h2 < (unsigned)HH) &&
                         ((unsigned)wg <= (unsigned)(WW - 4));
      tbase[s] = x2b;
      tgoff[s] = valid ? (h2 * WW + wg) : 0;
      tlds[s] = (tb < 1152) ? (B_BASE + row * B_ROW + f4 * (4 * KSTR) + 2 * cp)
                            : DUMP_USH;  // out-of-range slot1 -> pad region
      tcp[s] = (tb < 1152) ? cp : 0;
      tok[s] = valid;
    }
  }

  float4v acc[3][2];
#pragma unroll
  for (int ii = 0; ii < 3; ++ii) {
    acc[ii][0] = (float4v){0.f, 0.f, 0.f, 0.f};
    acc[ii][1] = (float4v){0.f, 0.f, 0.f, 0.f};
  }

  float4 va[2], vb[2];

#define LOADSET(C0)                                                            \
  {                                                                            \
    _Pragma("unroll") for (int s = 0; s < 2; ++s) {                            \
      const float* p =                                                         \
          tok[s] ? tbase[s] + (size_t)((C0) + 2 * tcp[s]) * HW + tgoff[s]      \
                 : zws;                                                        \
      const float* q = tok[s] ? p + HW : zws;                                  \
      va[s] = *(const float4*)p;                                               \
      vb[s] = *(const float4*)q;                                               \
    }                                                                          \
  }

#define CONVSET()                                                              \
  {                                                                            \
    _Pragma("unroll") for (int s = 0; s < 2; ++s) {                            \
      unsigned short* dst = smem + tlds[s];                                    \
      const float4 fa = va[s];                                                 \
      const float4 fb = vb[s];                                                 \
      *(uint32_t*)(dst + 0 * KSTR) = cvt_pk_bf16(fa.x, fb.x);                  \
      *(uint32_t*)(dst + 1 * KSTR) = cvt_pk_bf16(fa.y, fb.y);                  \
      *(uint32_t*)(dst + 2 * KSTR) = cvt_pk_bf16(fa.z, fb.z);                  \
      *(uint32_t*)(dst + 3 * KSTR) = cvt_pk_bf16(fa.w, fb.w);                  \
    }                                                                          \
  }

#define COMPUTE()                                                              \
  {                                                                            \
    const short8 a =                                                           \
        *(const short8*)(smem + hl * A_ROW + n16 * KSTR + quad * 8);           \
    __builtin_amdgcn_s_setprio(1);                                             \
    _Pragma("unroll") for (int ii = 0; ii < 3; ++ii) {                         \
      const int r = hl + roff - ii;                                            \
      const unsigned short* bp =                                               \
          smem + B_BASE + r * B_ROW + n16 * KSTR + quad * 8;                   \
      const short8 b0 = *(const short8*)(bp);                                  \
      const short8 b1 = *(const short8*)(bp + 16 * KSTR);                      \
      acc[ii][0] =                                                             \
          __builtin_amdgcn_mfma_f32_16x16x32_bf16(a, b0, acc[ii][0], 0, 0, 0); \
      acc[ii][1] =                                                             \
          __builtin_amdgcn_mfma_f32_16x16x32_bf16(a, b1, acc[ii][1], 0, 0, 0); \
    }                                                                          \
    __builtin_amdgcn_s_setprio(0);                                             \
  }

  // ---- main loop: 4 chunks of 32 channels, single buffer, counted bars ----
  LOADSET(0);

  CONVSET();      // waits only its own loads (compiler-counted vmcnt)
  LOADSET(32);    // next chunk in flight across compute
  BAR();
  COMPUTE();
  BAR();

  CONVSET();
  LOADSET(64);
  BAR();
  COMPUTE();
  BAR();

  CONVSET();
  LOADSET(96);
  BAR();
  COMPUTE();
  BAR();

  CONVSET();
  BAR();
  COMPUTE();
  BAR();  // all frag reads done; reuse smem as fp32 scratch

  // ---- epilogue: scatter D to LDS scratch [hl][m][kk], coalesced out ----
  float* scratch = (float*)smem;
  const float sc = 1.0f / 81.0f;
#pragma unroll
  for (int ii = 0; ii < 3; ++ii) {
    const int iabs = 3 * g + ii;  // i + 4, covers 0..8 across the 3 g-groups
    const float av0[4] = {acc[ii][0].x, acc[ii][0].y, acc[ii][0].z,
                          acc[ii][0].w};
    const float av1[4] = {acc[ii][1].x, acc[ii][1].y, acc[ii][1].z,
                          acc[ii][1].w};
#pragma unroll
    for (int reg = 0; reg < 4; ++reg) {
      const int m = quad * 4 + reg;
      // n-tile 0 (n = n16): ja = m + 4 - n16 + 4
      {
        const unsigned ja = (unsigned)(m + 8 - n16);
        if (ja < 9u)
          scratch[hl * EP_H + m * EP_M + iabs * 9 + (int)ja] = av0[reg] * sc;
      }
      // n-tile 1 (n = 16 + n16): ja = m - 12 - n16 + 4
      {
        const unsigned ja = (unsigned)(m - 8 - n16);
        if (ja < 9u)
          scratch[hl * EP_H + m * EP_M + iabs * 9 + (int)ja] = av1[reg] * sc;
      }
    }
  }
  BAR();

  // write-out: f -> (kk81, hlx, m4); 4 scalar LDS reads -> 64B stores,
  // 1296 float4 over 768 threads.
  for (int f = t; f < 1296; f += NT) {
    const int m4 = f & 3;
    const int hlx = (f >> 2) & 3;
    const int kk81 = f >> 4;  // iabs*9 + jabs, 0..80
    float4 v;
    v.x = scratch[hlx * EP_H + (4 * m4 + 0) * EP_M + kk81];
    v.y = scratch[hlx * EP_H + (4 * m4 + 1) * EP_M + kk81];
    v.z = scratch[hlx * EP_H + (4 * m4 + 2) * EP_M + kk81];
    v.w = scratch[hlx * EP_H + (4 * m4 + 3) * EP_M + kk81];
    const int kk = (kk81 + 41) % 81;
    *(float4*)(out + (((size_t)b * DD + kk) * HH + (h0 + hlx)) * WW + w0 +
               4 * m4) = v;
  }
}

extern "C" void kernel_launch(void* const* d_in, const int* in_sizes, int n_in,
                              void* d_out, int out_size, void* d_ws,
                              size_t ws_size, hipStream_t stream) {
  const float* x1 = (const float*)d_in[0];
  const float* x2 = (const float*)d_in[1];
  float* out = (float*)d_out;

  // zero 256 B of workspace: OOB staging lanes read zeros from here
  hipMemsetAsync(d_ws, 0, 256, stream);

  // 16 w-tiles x 32 h-tiles x 4 batches = 2048 blocks of 768 threads
  dim3 grid(16, 32, 4);
  dim3 block(NT);
  hipLaunchKernelGGL(cost_volume_kernel, grid, block, 0, stream, x1, x2, out,
                     (const float*)d_ws);
}